// Round 6
// baseline (340.553 us; speedup 1.0000x reference)
//
#include <hip/hip_runtime.h>
#include <cstdint>

#define S_   4096
#define B_   2
#define H_   8
#define HD_  64
#define DM_  512
#define G_   64
#define SEGN 16

typedef __attribute__((ext_vector_type(8))) short bf8_t;     // 8 bf16 (4 VGPR)
typedef __attribute__((ext_vector_type(4))) float f4_t;
typedef __attribute__((ext_vector_type(4))) unsigned u4_t;
#define MFMA16(A,Bv,C) __builtin_amdgcn_mfma_f32_16x16x32_bf16((A),(Bv),(C),0,0,0)

typedef const unsigned __attribute__((address_space(1)))* gp1_t;
typedef unsigned __attribute__((address_space(3)))* lp3_t;
static __device__ __forceinline__ void gld16(const void* g, void* l){
    __builtin_amdgcn_global_load_lds((gp1_t)g, (lp3_t)l, 16, 0, 0);
}

static __device__ __forceinline__ unsigned short f2bf(float x){   // RNE
    union { float f; unsigned u; } v; v.f = x;
    unsigned r = v.u + 0x7FFFu + ((v.u >> 16) & 1u);
    return (unsigned short)(r >> 16);
}
// packed trunc-split: low16 = bf16 hi-part, high16 = bf16 of residual
static __device__ __forceinline__ unsigned pksplit(float x){
    unsigned u = __float_as_uint(x);
    unsigned t = u & 0xFFFF0000u;
    float r = x - __uint_as_float(t);
    return (u >> 16) | (__float_as_uint(r) & 0xFFFF0000u);
}
static __device__ __forceinline__ float rmax16(float x){
    x=fmaxf(x,__shfl_xor(x,1)); x=fmaxf(x,__shfl_xor(x,2));
    x=fmaxf(x,__shfl_xor(x,4)); x=fmaxf(x,__shfl_xor(x,8)); return x;
}
static __device__ __forceinline__ float rsum16(float x){
    x+=__shfl_xor(x,1); x+=__shfl_xor(x,2); x+=__shfl_xor(x,4); x+=__shfl_xor(x,8); return x;
}

// perm 0: identity (B,S,D rows)  perm 1: (S,B,D)->(B,S,D)  perm 2: qg rows b*S+g
__device__ __forceinline__ int in_row_map(int m, int perm) {
    if (perm == 0) return m;
    if (perm == 1) { int b = m >> 12, s = m & 4095; return s * 2 + b; }
    { int b = m >> 6, g = m & 63; return b * S_ + g; }
}

// -------- in-place packed split of the 4 activation tensors (d_in restored every launch)
struct SplitArgs { float* p[4]; };
__global__ __launch_bounds__(256) void split_inplace(SplitArgs a){
    int t = blockIdx.x >> 12;                       // 4096 blocks per tensor
    int idx = (blockIdx.x & 4095) * 256 + threadIdx.x;
    float* p = a.p[t];
    float4 x = *(const float4*)(p + (size_t)idx * 4);
    unsigned o[4] = { pksplit(x.x), pksplit(x.y), pksplit(x.z), pksplit(x.w) };
    *(u4_t*)(p + (size_t)idx * 4) = *(const u4_t*)o;
}

// -------- weight expansion: W -> Wa=[w_hi,w_hi] u32, Wb=[w_lo,w_lo] u32 (4-term exact)
struct WexpArgs { const float* src[6]; float alpha[6]; unsigned* wa; unsigned* wb; };
__global__ __launch_bounds__(256) void wexpand(WexpArgs a){
    int g = blockIdx.x >> 8;                        // 256 blocks per tensor
    int idx = ((blockIdx.x & 255) * 256 + threadIdx.x) * 4;
    const float* s = a.src[g];
    float al = a.alpha[g];
    size_t base = (size_t)g * 262144 + idx;
    float4 x = *(const float4*)(s + idx);
    float xs[4] = { x.x*al, x.y*al, x.z*al, x.w*al };
    unsigned wa4[4], wb4[4];
    #pragma unroll
    for (int j = 0; j < 4; ++j) {
        unsigned u = __float_as_uint(xs[j]);
        unsigned t = u & 0xFFFF0000u;
        float r = xs[j] - __uint_as_float(t);
        unsigned lo = __float_as_uint(r) & 0xFFFF0000u;
        wa4[j] = (u >> 16) | t;                     // [w_hi, w_hi]
        wb4[j] = (lo >> 16) | lo;                   // [w_lo, w_lo]
    }
    *(u4_t*)(a.wa + base) = *(const u4_t*)wa4;
    *(u4_t*)(a.wb + base) = *(const u4_t*)wb4;
}

// -------- projection GEMM: doubled-K bf16, A2 x (Wa + Wb) = exact 4-term a.w ---------
// mode 0: out u32 pksplit   mode 2: out u32 dup-hi (K2a)   mode 1: out_t[b][h][d][S] bf16
struct ProjDesc {
    const unsigned* A2; const unsigned* Wa; const unsigned* Wb; const float* bias;
    unsigned* out_u32; unsigned short* out_t;
    float balpha; int perm; int mode; int mtiles;
};
struct ProjBatch { ProjDesc d[3]; };

__global__ __launch_bounds__(256) void proj6(ProjBatch pb){
    __shared__ unsigned Asl[128*32];   // [row][32 u32] = 128B rows, swizzled 16B chunks
    __shared__ unsigned Wasl[128*32];
    __shared__ unsigned Wbsl[128*32];
    const ProjDesc d = pb.d[blockIdx.z];
    if ((int)blockIdx.x >= d.mtiles) return;
    const int tid = threadIdx.x;
    const int m0 = blockIdx.x*128, n0 = blockIdx.y*128;
    const int w = tid>>6, l = tid&63, wr = w>>1, wc = w&1, lg = l>>4, lc = l&15;
    const int grow = l>>3, gchk = l&7;              // 8 rows x 8 chunks per wave-issue

    f4_t acc[4][4];
    #pragma unroll
    for(int i=0;i<4;++i)
        #pragma unroll
        for(int j=0;j<4;++j) acc[i][j] = (f4_t){0.f,0.f,0.f,0.f};

    for (int k0 = 0; k0 < 16; ++k0) {
        __syncthreads();                             // prev step's LDS reads done
        #pragma unroll
        for (int t = 0; t < 4; ++t) {
            int row = t*32 + w*8 + grow;             // tile-local row 0..127
            int sw = (gchk ^ (row & 7)) << 2;        // pre-swizzled source chunk (u32)
            gld16(d.A2 + (size_t)in_row_map(m0+row, d.perm)*DM_ + k0*32 + sw,
                  (char*)Asl + (t*32 + w*8)*128);
            gld16(d.Wa + (size_t)(n0+row)*DM_ + k0*32 + sw,
                  (char*)Wasl + (t*32 + w*8)*128);
            gld16(d.Wb + (size_t)(n0+row)*DM_ + k0*32 + sw,
                  (char*)Wbsl + (t*32 + w*8)*128);
        }
        __syncthreads();                             // drains vmcnt(0)
        #pragma unroll
        for (int ks = 0; ks < 2; ++ks) {
            bf8_t af[4];
            #pragma unroll
            for (int mf = 0; mf < 4; ++mf) {
                int r = wr*64 + mf*16 + lc;
                af[mf] = *(const bf8_t*)((const char*)Asl + r*128 + (((ks*4+lg) ^ (r&7))<<4));
            }
            #pragma unroll
            for (int nf = 0; nf < 4; ++nf) {
                int r = wc*64 + nf*16 + lc;
                int off = r*128 + (((ks*4+lg) ^ (r&7))<<4);
                bf8_t wa = *(const bf8_t*)((const char*)Wasl + off);
                bf8_t wb = *(const bf8_t*)((const char*)Wbsl + off);
                #pragma unroll
                for (int mf = 0; mf < 4; ++mf) {
                    acc[mf][nf] = MFMA16(af[mf], wa, acc[mf][nf]);
                    acc[mf][nf] = MFMA16(af[mf], wb, acc[mf][nf]);
                }
            }
        }
    }
    if (d.mode != 1) {
        #pragma unroll
        for(int nf=0;nf<4;++nf){
            int n = n0 + wc*64 + nf*16 + lc;
            float bv = d.bias[n] * d.balpha;
            #pragma unroll
            for(int mf=0;mf<4;++mf){
                int mb = m0 + wr*64 + mf*16 + lg*4;
                #pragma unroll
                for(int i=0;i<4;++i){
                    float x = acc[mf][nf][i] + bv;
                    unsigned pk;
                    if (d.mode == 0) pk = pksplit(x);
                    else { unsigned hb = f2bf(x); pk = hb | (hb << 16); }
                    d.out_u32[(size_t)(mb+i)*DM_ + n] = pk;
                }
            }
        }
    } else {
        #pragma unroll
        for(int nf=0;nf<4;++nf){
            int n = n0 + wc*64 + nf*16 + lc;
            int h = n>>6, dl = n&63;
            float bv = d.bias[n];
            #pragma unroll
            for(int mf=0;mf<4;++mf){
                int m = m0 + wr*64 + mf*16 + lg*4;
                int b = m>>12, s = m&4095;
                unsigned short q0=f2bf(acc[mf][nf][0]+bv), q1=f2bf(acc[mf][nf][1]+bv);
                unsigned short q2=f2bf(acc[mf][nf][2]+bv), q3=f2bf(acc[mf][nf][3]+bv);
                unsigned pkw[2] = { (unsigned)q0 | ((unsigned)q1<<16),
                                    (unsigned)q2 | ((unsigned)q3<<16) };
                *(uint2*)(d.out_t + ((size_t)((b*H_+h)*HD_ + dl))*S_ + s) = *(const uint2*)pkw;
            }
        }
    }
}

// ---------------- local (banded+sel) attention ----------------
__global__ __launch_bounds__(256) void attn_local(
    const unsigned* __restrict__ Qpk, const unsigned* __restrict__ K2a,
    const unsigned short* __restrict__ VT, const int* __restrict__ amask,
    float* __restrict__ out)
{
    __shared__ unsigned Kls[64*64];        // [p][64 u32] 256B rows ([k_hi,k_hi] pairs)
    __shared__ unsigned short Vls[64*64];  // [d][64 bf16] 128B rows
    __shared__ unsigned short Ps[64*64];   // [q][64 bf16] 128B rows
    const int tid=threadIdx.x, b=blockIdx.z, h=blockIdx.y;
    const int s0=(blockIdx.x+1)*64;        // rows 0..63 come from the global path
    const int w=tid>>6, l=tid&63, lg=l>>4, lc=l&15;

    bf8_t qf[4];                            // Q frags: packed u32 = [q_hi,q_lo] bf16 pair
    {
        const unsigned* qp = Qpk + ((size_t)(b*S_ + s0 + w*16 + lc))*DM_ + h*HD_;
        #pragma unroll
        for(int ks=0;ks<4;++ks) qf[ks] = *(const bf8_t*)(qp + ks*16 + lg*4);
    }
    float m_i[4]={-1e30f,-1e30f,-1e30f,-1e30f}, l_i[4]={0.f,0.f,0.f,0.f};
    f4_t acc_o[4];
    #pragma unroll
    for(int nf=0;nf<4;++nf) acc_o[nf]=(f4_t){0.f,0.f,0.f,0.f};

    for(int jc=0;jc<10;++jc){
        const int p0 = (jc==0) ? 0 : (s0-256+(jc-1)*64);
        if (p0 <= -64 || p0 >= S_) continue;       // block-uniform
        #pragma unroll
        for (int t = 0; t < 4; ++t) {              // K tile: 64 rows x 256B
            int row = t*16 + w*4 + (l>>4);
            int p = p0 + row; p = p<0?0:(p>S_-1?S_-1:p);
            gld16(K2a + (size_t)(b*S_+p)*DM_ + h*HD_ + (((l&15) ^ (row&7))<<2),
                  (char*)Kls + (t*16 + w*4)*256);
        }
        #pragma unroll
        for (int t = 0; t < 2; ++t) {              // V tile: 64 d-rows x 128B
            int row = t*32 + w*8 + (l>>3);
            int col = p0 + (((l&7) ^ (row&7))<<3);
            col = col<0?0:(col>S_-8?S_-8:col);
            gld16(VT + ((size_t)((b*H_+h)*HD_ + row))*S_ + col,
                  (char*)Vls + (t*32 + w*8)*128);
        }
        __syncthreads();                           // drain vmcnt(0)
        f4_t s4[4];
        #pragma unroll
        for(int cf=0;cf<4;++cf) s4[cf]=(f4_t){0.f,0.f,0.f,0.f};
        #pragma unroll
        for(int ks=0;ks<4;++ks)
            #pragma unroll
            for(int cf=0;cf<4;++cf){
                int r = cf*16+lc;
                bf8_t kf = *(const bf8_t*)((const char*)Kls + r*256 + (((ks*4+lg)^(r&7))<<4));
                s4[cf]=MFMA16(qf[ks],kf,s4[cf]);
            }
        if(jc>0){  // band mask: outside band -> -1e9; global keys in band -> -10000
            #pragma unroll
            for(int cf=0;cf<4;++cf){
                int p = p0 + cf*16 + lc;
                float madd = (amask[b*S_+p]!=0) ? -10000.f : 0.f;
                #pragma unroll
                for(int i=0;i<4;++i){
                    int rel = p - (s0 + w*16 + lg*4 + i);
                    s4[cf][i] = (rel<-256 || rel>256) ? -1e9f : s4[cf][i]+madd;
                }
            }
        }
        float Pv[4][4];
        #pragma unroll
        for(int i=0;i<4;++i){
            float rm = fmaxf(fmaxf(s4[0][i],s4[1][i]),fmaxf(s4[2][i],s4[3][i]));
            rm = rmax16(rm);
            float mn = fmaxf(m_i[i], rm);
            float rs = 0.f;
            #pragma unroll
            for(int cf=0;cf<4;++cf){ float e=__expf(s4[cf][i]-mn); Pv[cf][i]=e; rs+=e; }
            rs = rsum16(rs);
            float f = __expf(m_i[i]-mn);
            l_i[i] = l_i[i]*f + rs;
            m_i[i] = mn;
            #pragma unroll
            for(int nf=0;nf<4;++nf) acc_o[nf][i]*=f;
        }
        #pragma unroll
        for(int cf=0;cf<4;++cf)
            #pragma unroll
            for(int i=0;i<4;++i){
                int qr = w*16+lg*4+i, p = cf*16+lc;
                Ps[qr*64 + ((((p>>3)^(qr&7))<<3) | (p&7))] = f2bf(Pv[cf][i]);
            }
        __syncthreads();                           // Ps visible
        #pragma unroll
        for(int ks=0;ks<2;++ks){
            int qr = w*16+lc;
            bf8_t pf = *(const bf8_t*)((const char*)Ps + qr*128 + (((ks*4+lg)^(qr&7))<<4));
            #pragma unroll
            for(int nf=0;nf<4;++nf){
                int dr = nf*16+lc;
                bf8_t vf = *(const bf8_t*)((const char*)Vls + dr*128 + (((ks*4+lg)^(dr&7))<<4));
                acc_o[nf] = MFMA16(pf, vf, acc_o[nf]);
            }
        }
        __syncthreads();                           // PV reads done before next stage
    }
    #pragma unroll
    for(int i=0;i<4;++i){
        float inv = 1.f/l_i[i];
        float* orow = out + ((size_t)(b*S_ + s0 + w*16 + lg*4 + i))*DM_ + h*HD_;
        #pragma unroll
        for(int nf=0;nf<4;++nf) orow[nf*16+lc] = acc_o[nf][i]*inv;
    }
}

// ---------------- global attention: 64 q vs 256-key segment ----------------
__global__ __launch_bounds__(256) void attn_global(
    const unsigned* __restrict__ QGpk, const unsigned* __restrict__ KG2a,
    const unsigned short* __restrict__ VGT, float* __restrict__ part_m,
    float* __restrict__ part_l, float* __restrict__ part_o)
{
    __shared__ unsigned Kls[64*64];
    __shared__ unsigned short Vls[64*64];
    __shared__ unsigned short Ps[64*64];
    const int tid=threadIdx.x, b=blockIdx.z, h=blockIdx.y, seg=blockIdx.x;
    const int w=tid>>6, l=tid&63, lg=l>>4, lc=l&15;

    bf8_t qf[4];
    {
        const unsigned* qp = QGpk + ((size_t)(b*G_ + w*16 + lc))*DM_ + h*HD_;
        #pragma unroll
        for(int ks=0;ks<4;++ks) qf[ks] = *(const bf8_t*)(qp + ks*16 + lg*4);
    }
    float m_i[4]={-1e30f,-1e30f,-1e30f,-1e30f}, l_i[4]={0.f,0.f,0.f,0.f};
    f4_t acc_o[4];
    #pragma unroll
    for(int nf=0;nf<4;++nf) acc_o[nf]=(f4_t){0.f,0.f,0.f,0.f};

    for(int jc=0;jc<4;++jc){
        const int p0 = seg*256 + jc*64;
        #pragma unroll
        for (int t = 0; t < 4; ++t) {
            int row = t*16 + w*4 + (l>>4);
            gld16(KG2a + (size_t)(b*S_+p0+row)*DM_ + h*HD_ + (((l&15) ^ (row&7))<<2),
                  (char*)Kls + (t*16 + w*4)*256);
        }
        #pragma unroll
        for (int t = 0; t < 2; ++t) {
            int row = t*32 + w*8 + (l>>3);
            gld16(VGT + ((size_t)((b*H_+h)*HD_ + row))*S_ + p0 + (((l&7) ^ (row&7))<<3),
                  (char*)Vls + (t*32 + w*8)*128);
        }
        __syncthreads();
        f4_t s4[4];
        #pragma unroll
        for(int cf=0;cf<4;++cf) s4[cf]=(f4_t){0.f,0.f,0.f,0.f};
        #pragma unroll
        for(int ks=0;ks<4;++ks)
            #pragma unroll
            for(int cf=0;cf<4;++cf){
                int r = cf*16+lc;
                bf8_t kf = *(const bf8_t*)((const char*)Kls + r*256 + (((ks*4+lg)^(r&7))<<4));
                s4[cf]=MFMA16(qf[ks],kf,s4[cf]);
            }
        float Pv[4][4];
        #pragma unroll
        for(int i=0;i<4;++i){
            float rm = fmaxf(fmaxf(s4[0][i],s4[1][i]),fmaxf(s4[2][i],s4[3][i]));
            rm = rmax16(rm);
            float mn = fmaxf(m_i[i], rm);
            float rs = 0.f;
            #pragma unroll
            for(int cf=0;cf<4;++cf){ float e=__expf(s4[cf][i]-mn); Pv[cf][i]=e; rs+=e; }
            rs = rsum16(rs);
            float f = __expf(m_i[i]-mn);
            l_i[i] = l_i[i]*f + rs;
            m_i[i] = mn;
            #pragma unroll
            for(int nf=0;nf<4;++nf) acc_o[nf][i]*=f;
        }
        #pragma unroll
        for(int cf=0;cf<4;++cf)
            #pragma unroll
            for(int i=0;i<4;++i){
                int qr = w*16+lg*4+i, p = cf*16+lc;
                Ps[qr*64 + ((((p>>3)^(qr&7))<<3) | (p&7))] = f2bf(Pv[cf][i]);
            }
        __syncthreads();
        #pragma unroll
        for(int ks=0;ks<2;++ks){
            int qr = w*16+lc;
            bf8_t pf = *(const bf8_t*)((const char*)Ps + qr*128 + (((ks*4+lg)^(qr&7))<<4));
            #pragma unroll
            for(int nf=0;nf<4;++nf){
                int dr = nf*16+lc;
                bf8_t vf = *(const bf8_t*)((const char*)Vls + dr*128 + (((ks*4+lg)^(dr&7))<<4));
                acc_o[nf] = MFMA16(pf, vf, acc_o[nf]);
            }
        }
        __syncthreads();
    }
    const int pid = (b*H_+h)*SEGN + seg;
    #pragma unroll
    for(int i=0;i<4;++i){
        int qrl = w*16 + lg*4 + i;
        #pragma unroll
        for(int nf=0;nf<4;++nf)
            part_o[(size_t)pid*4096 + qrl*64 + nf*16 + lc] = acc_o[nf][i];
        if(lc==0){
            part_m[pid*64+qrl] = m_i[i];
            part_l[pid*64+qrl] = l_i[i];
        }
    }
}

__global__ __launch_bounds__(256) void global_combine(
    const float* __restrict__ part_m, const float* __restrict__ part_l,
    const float* __restrict__ part_o, float* __restrict__ out)
{
    const int bh = blockIdx.x;
    const int b = bh >> 3, h = bh & 7;
    const int tid = threadIdx.x;
    const int q = tid >> 2, d0 = (tid & 3) * 16;
    float mg = -1e30f;
    for (int s = 0; s < SEGN; ++s)
        mg = fmaxf(mg, part_m[(bh * SEGN + s) * 64 + q]);
    float lsum = 0.f, accv[16] = {};
    for (int s = 0; s < SEGN; ++s) {
        const int pid = bh * SEGN + s;
        float wgt = __expf(part_m[pid * 64 + q] - mg);
        lsum += wgt * part_l[pid * 64 + q];
        const float* op = part_o + (size_t)pid * 4096 + q * 64 + d0;
        #pragma unroll
        for (int t = 0; t < 4; ++t) {
            float tmp[4];
            *(float4*)tmp = *(const float4*)(op + t * 4);
            #pragma unroll
            for (int u = 0; u < 4; ++u) accv[t * 4 + u] += wgt * tmp[u];
        }
    }
    float inv = 1.f / lsum;
    float* orow = out + ((size_t)(b * S_ + q)) * DM_ + h * HD_ + d0;
    #pragma unroll
    for (int t = 0; t < 4; ++t) {
        float o[4];
        #pragma unroll
        for (int u = 0; u < 4; ++u) o[u] = accv[t * 4 + u] * inv;
        *(float4*)(orow + t * 4) = *(const float4*)o;
    }
}

extern "C" void kernel_launch(void* const* d_in, const int* in_sizes, int n_in,
                              void* d_out, int out_size, void* d_ws, size_t ws_size,
                              hipStream_t stream) {
    float* hidden = (float*)d_in[0];
    float* q  = (float*)d_in[1];
    float* k  = (float*)d_in[2];
    float* v  = (float*)d_in[3];
    const int* amask = (const int*)d_in[4];
    const float* Wq  = (const float*)d_in[5];  const float* bq  = (const float*)d_in[6];
    const float* Wk  = (const float*)d_in[7];  const float* bk  = (const float*)d_in[8];
    const float* Wv  = (const float*)d_in[9];  const float* bv  = (const float*)d_in[10];
    const float* Wqg = (const float*)d_in[11]; const float* bqg = (const float*)d_in[12];
    const float* Wkg = (const float*)d_in[13]; const float* bkg = (const float*)d_in[14];
    const float* Wvg = (const float*)d_in[15]; const float* bvg = (const float*)d_in[16];
    float* out = (float*)d_out;

    // ws layout (~54 MB peak):
    const size_t NE = (size_t)B_ * S_ * DM_;                  // 4194304
    unsigned* Qpk = (unsigned*)d_ws;                          // 16.8 MB
    unsigned* K2a = Qpk + NE;                                 // 16.8 MB
    unsigned short* VT = (unsigned short*)(K2a + NE);         // 8.4 MB
    unsigned* Wa = (unsigned*)(VT + NE);                      // 6 MB (6 x 1MB)
    unsigned* Wb = Wa + 6*262144;                             // 6 MB
    // phase-2 aliases inside dead buffers:
    unsigned* QGpk = Qpk;                                     // 256 KB
    float* pm = (float*)(Qpk + 65536);                        // 64 KB
    float* pl = (float*)(Qpk + 81920);                        // 64 KB
    float* po = (float*)(Qpk + 98304);                        // 4 MB
    unsigned* KG2a = K2a;                                     // alias
    unsigned short* VGT = VT;                                 // alias

    dim3 blk(256);
    // 1) in-place packed split of activations
    SplitArgs sa; sa.p[0]=hidden; sa.p[1]=q; sa.p[2]=k; sa.p[3]=v;
    hipLaunchKernelGGL(split_inplace, dim3(4*4096), blk, 0, stream, sa);
    // 2) weight expansion (q-scale folded into Wq/Wqg)
    WexpArgs we;
    we.src[0]=Wq; we.src[1]=Wk; we.src[2]=Wv; we.src[3]=Wkg; we.src[4]=Wvg; we.src[5]=Wqg;
    we.alpha[0]=0.125f; we.alpha[1]=1.f; we.alpha[2]=1.f;
    we.alpha[3]=1.f; we.alpha[4]=1.f; we.alpha[5]=0.125f;
    we.wa = Wa; we.wb = Wb;
    hipLaunchKernelGGL(wexpand, dim3(1536), blk, 0, stream, we);

    // 3) phase-1 projections: q,k,v
    ProjBatch p1;
    p1.d[0] = { (const unsigned*)q, Wa + 0*262144, Wb + 0*262144, bq, Qpk, nullptr, 0.125f, 1, 0, 64 };
    p1.d[1] = { (const unsigned*)k, Wa + 1*262144, Wb + 1*262144, bk, K2a, nullptr, 1.0f,   1, 2, 64 };
    p1.d[2] = { (const unsigned*)v, Wa + 2*262144, Wb + 2*262144, bv, nullptr, VT,  1.0f,   1, 1, 64 };
    hipLaunchKernelGGL(proj6, dim3(64,4,3), blk, 0, stream, p1);

    // 4) local attention (rows 64..4095)
    hipLaunchKernelGGL(attn_local, dim3(63, H_, B_), blk, 0, stream, Qpk, K2a, VT, amask, out);

    // 5) phase-2 projections: kg,vg,qg (alias into dead phase-1 buffers)
    ProjBatch p2;
    p2.d[0] = { (const unsigned*)hidden, Wa + 3*262144, Wb + 3*262144, bkg, KG2a, nullptr, 1.0f,   0, 2, 64 };
    p2.d[1] = { (const unsigned*)hidden, Wa + 4*262144, Wb + 4*262144, bvg, nullptr, VGT,  1.0f,   0, 1, 64 };
    p2.d[2] = { (const unsigned*)hidden, Wa + 5*262144, Wb + 5*262144, bqg, QGpk, nullptr, 0.125f, 2, 0, 1  };
    hipLaunchKernelGGL(proj6, dim3(64,4,3), blk, 0, stream, p2);

    // 6) global attention (rows 0..63) + combine
    hipLaunchKernelGGL(attn_global, dim3(SEGN, H_, B_), blk, 0, stream, QGpk, KG2a, VGT, pm, pl, po);
    hipLaunchKernelGGL(global_combine, dim3(B_ * H_), blk, 0, stream, pm, pl, po, out);
}

// Round 7
// 294.794 us; speedup vs baseline: 1.1552x; 1.1552x over previous
//
#include <hip/hip_runtime.h>
#include <cstdint>

#define S_   4096
#define B_   2
#define H_   8
#define HD_  64
#define DM_  512
#define G_   64
#define SEGN 16

typedef __attribute__((ext_vector_type(8))) short bf8_t;     // 8 bf16 (4 VGPR)
typedef __attribute__((ext_vector_type(4))) float f4_t;
typedef __attribute__((ext_vector_type(4))) unsigned u4_t;
#define MFMA16(A,Bv,C) __builtin_amdgcn_mfma_f32_16x16x32_bf16((A),(Bv),(C),0,0,0)

typedef const unsigned __attribute__((address_space(1)))* gp1_t;
typedef unsigned __attribute__((address_space(3)))* lp3_t;
static __device__ __forceinline__ void gld16(const void* g, void* l){
    __builtin_amdgcn_global_load_lds((gp1_t)g, (lp3_t)l, 16, 0, 0);
}

static __device__ __forceinline__ unsigned short f2bf(float x){   // RNE
    union { float f; unsigned u; } v; v.f = x;
    unsigned r = v.u + 0x7FFFu + ((v.u >> 16) & 1u);
    return (unsigned short)(r >> 16);
}
// packed trunc-split: low16 = bf16 hi-part, high16 = bf16 of residual
static __device__ __forceinline__ unsigned pksplit(float x){
    unsigned u = __float_as_uint(x);
    unsigned t = u & 0xFFFF0000u;
    float r = x - __uint_as_float(t);
    return (u >> 16) | (__float_as_uint(r) & 0xFFFF0000u);
}
static __device__ __forceinline__ float rmax16(float x){
    x=fmaxf(x,__shfl_xor(x,1)); x=fmaxf(x,__shfl_xor(x,2));
    x=fmaxf(x,__shfl_xor(x,4)); x=fmaxf(x,__shfl_xor(x,8)); return x;
}
static __device__ __forceinline__ float rsum16(float x){
    x+=__shfl_xor(x,1); x+=__shfl_xor(x,2); x+=__shfl_xor(x,4); x+=__shfl_xor(x,8); return x;
}

// perm 0: identity (B,S,D rows)  perm 1: (S,B,D)->(B,S,D)  perm 2: qg rows b*S+g
__device__ __forceinline__ int in_row_map(int m, int perm) {
    if (perm == 0) return m;
    if (perm == 1) { int b = m >> 12, s = m & 4095; return s * 2 + b; }
    { int b = m >> 6, g = m & 63; return b * S_ + g; }
}

// -------- in-place packed split of the 4 activation tensors (d_in restored every launch)
struct SplitArgs { float* p[4]; };
__global__ __launch_bounds__(256) void split_inplace(SplitArgs a){
    int t = blockIdx.x >> 12;                       // 4096 blocks per tensor
    int idx = (blockIdx.x & 4095) * 256 + threadIdx.x;
    float* p = a.p[t];
    float4 x = *(const float4*)(p + (size_t)idx * 4);
    unsigned o[4] = { pksplit(x.x), pksplit(x.y), pksplit(x.z), pksplit(x.w) };
    *(u4_t*)(p + (size_t)idx * 4) = *(const u4_t*)o;
}

// -------- weight expansion: W -> Wa=[w_hi,w_hi] u32, Wb=[w_lo,w_lo] u32 (4-term exact)
struct WexpArgs { const float* src[6]; float alpha[6]; unsigned* wa; unsigned* wb; };
__global__ __launch_bounds__(256) void wexpand(WexpArgs a){
    int g = blockIdx.x >> 8;                        // 256 blocks per tensor
    int idx = ((blockIdx.x & 255) * 256 + threadIdx.x) * 4;
    const float* s = a.src[g];
    float al = a.alpha[g];
    size_t base = (size_t)g * 262144 + idx;
    float4 x = *(const float4*)(s + idx);
    float xs[4] = { x.x*al, x.y*al, x.z*al, x.w*al };
    unsigned wa4[4], wb4[4];
    #pragma unroll
    for (int j = 0; j < 4; ++j) {
        unsigned u = __float_as_uint(xs[j]);
        unsigned t = u & 0xFFFF0000u;
        float r = xs[j] - __uint_as_float(t);
        unsigned lo = __float_as_uint(r) & 0xFFFF0000u;
        wa4[j] = (u >> 16) | t;                     // [w_hi, w_hi]
        wb4[j] = (lo >> 16) | lo;                   // [w_lo, w_lo]
    }
    *(u4_t*)(a.wa + base) = *(const u4_t*)wa4;
    *(u4_t*)(a.wb + base) = *(const u4_t*)wb4;
}

// -------- projection GEMM: doubled-K bf16, A2 x (Wa + Wb) = exact 4-term a.w ---------
// mode 0: out bf16 rows [m][512]     mode 1: out_t[b][h][d][S] bf16 (transposed)
struct ProjDesc {
    const unsigned* A2; const unsigned* Wa; const unsigned* Wb; const float* bias;
    unsigned short* out_r; unsigned short* out_t;
    float balpha; int perm; int mode; int mtiles;
};
struct ProjBatch { ProjDesc d[6]; };

__global__ __launch_bounds__(256) void proj6(ProjBatch pb){
    __shared__ unsigned Asl[128*32];   // [row][32 u32] = 128B rows, swizzled 16B chunks
    __shared__ unsigned Wasl[128*32];
    __shared__ unsigned Wbsl[128*32];
    const ProjDesc d = pb.d[blockIdx.z];
    if ((int)blockIdx.x >= d.mtiles) return;
    const int tid = threadIdx.x;
    const int m0 = blockIdx.x*128, n0 = blockIdx.y*128;
    const int w = tid>>6, l = tid&63, wr = w>>1, wc = w&1, lg = l>>4, lc = l&15;
    const int grow = l>>3, gchk = l&7;              // 8 rows x 8 chunks per wave-issue

    f4_t acc[4][4];
    #pragma unroll
    for(int i=0;i<4;++i)
        #pragma unroll
        for(int j=0;j<4;++j) acc[i][j] = (f4_t){0.f,0.f,0.f,0.f};

    for (int k0 = 0; k0 < 16; ++k0) {
        __syncthreads();                             // prev step's LDS reads done
        #pragma unroll
        for (int t = 0; t < 4; ++t) {
            int row = t*32 + w*8 + grow;             // tile-local row 0..127
            int sw = (gchk ^ (row & 7)) << 2;        // pre-swizzled source chunk (u32)
            gld16(d.A2 + (size_t)in_row_map(m0+row, d.perm)*DM_ + k0*32 + sw,
                  (char*)Asl + (t*32 + w*8)*128);
            gld16(d.Wa + (size_t)(n0+row)*DM_ + k0*32 + sw,
                  (char*)Wasl + (t*32 + w*8)*128);
            gld16(d.Wb + (size_t)(n0+row)*DM_ + k0*32 + sw,
                  (char*)Wbsl + (t*32 + w*8)*128);
        }
        __syncthreads();                             // drains vmcnt(0)
        #pragma unroll
        for (int ks = 0; ks < 2; ++ks) {
            bf8_t af[4];
            #pragma unroll
            for (int mf = 0; mf < 4; ++mf) {
                int r = wr*64 + mf*16 + lc;
                af[mf] = *(const bf8_t*)((const char*)Asl + r*128 + (((ks*4+lg) ^ (r&7))<<4));
            }
            #pragma unroll
            for (int nf = 0; nf < 4; ++nf) {
                int r = wc*64 + nf*16 + lc;
                int off = r*128 + (((ks*4+lg) ^ (r&7))<<4);
                bf8_t wa = *(const bf8_t*)((const char*)Wasl + off);
                bf8_t wb = *(const bf8_t*)((const char*)Wbsl + off);
                #pragma unroll
                for (int mf = 0; mf < 4; ++mf) {
                    acc[mf][nf] = MFMA16(af[mf], wa, acc[mf][nf]);
                    acc[mf][nf] = MFMA16(af[mf], wb, acc[mf][nf]);
                }
            }
        }
    }
    if (d.mode == 0) {
        #pragma unroll
        for(int nf=0;nf<4;++nf){
            int n = n0 + wc*64 + nf*16 + lc;
            float bv = d.bias[n] * d.balpha;
            #pragma unroll
            for(int mf=0;mf<4;++mf){
                int mb = m0 + wr*64 + mf*16 + lg*4;
                #pragma unroll
                for(int i=0;i<4;++i)
                    d.out_r[(size_t)(mb+i)*DM_ + n] = f2bf(acc[mf][nf][i] + bv);
            }
        }
    } else {
        #pragma unroll
        for(int nf=0;nf<4;++nf){
            int n = n0 + wc*64 + nf*16 + lc;
            int h = n>>6, dl = n&63;
            float bv = d.bias[n];
            #pragma unroll
            for(int mf=0;mf<4;++mf){
                int m = m0 + wr*64 + mf*16 + lg*4;
                int b = m>>12, s = m&4095;
                unsigned short q0=f2bf(acc[mf][nf][0]+bv), q1=f2bf(acc[mf][nf][1]+bv);
                unsigned short q2=f2bf(acc[mf][nf][2]+bv), q3=f2bf(acc[mf][nf][3]+bv);
                unsigned pkw[2] = { (unsigned)q0 | ((unsigned)q1<<16),
                                    (unsigned)q2 | ((unsigned)q3<<16) };
                *(uint2*)(d.out_t + ((size_t)((b*H_+h)*HD_ + dl))*S_ + s) = *(const uint2*)pkw;
            }
        }
    }
}

// ---------------- fused attention: x<63 -> local band tile; x>=63 -> global segment ----
__global__ __launch_bounds__(256) void attn_fused(
    const unsigned short* __restrict__ Qbf, const unsigned short* __restrict__ Kbf,
    const unsigned short* __restrict__ VT, const unsigned short* __restrict__ QGbf,
    const unsigned short* __restrict__ KGbf, const unsigned short* __restrict__ VGT,
    const int* __restrict__ amask, float* __restrict__ out,
    float* __restrict__ part_m, float* __restrict__ part_l, float* __restrict__ part_o)
{
    __shared__ unsigned short Kls[64*64];  // [p][64 bf16] 128B rows, swizzled chunks
    __shared__ unsigned short Vls[64*64];  // [d][64 bf16] 128B rows
    __shared__ unsigned short Ps[64*64];   // [q][64 bf16] 128B rows
    const int tid=threadIdx.x, b=blockIdx.z, h=blockIdx.y;
    const int w=tid>>6, l=tid&63, lg=l>>4, lc=l&15;
    const bool is_local = (int)blockIdx.x < 63;
    const int s0 = (blockIdx.x+1)*64;                  // local only
    const int seg = (int)blockIdx.x - 63;              // global only

    const unsigned short* Qsrc = is_local ? (Qbf + ((size_t)(b*S_ + s0 + w*16 + lc))*DM_ + h*HD_)
                                          : (QGbf + ((size_t)(b*G_ + w*16 + lc))*DM_ + h*HD_);
    const unsigned short* Ksrc = is_local ? (Kbf + (size_t)b*S_*DM_ + h*HD_)
                                          : (KGbf + (size_t)b*S_*DM_ + h*HD_);
    const unsigned short* Vsrc = is_local ? (VT + ((size_t)(b*H_+h)*HD_)*S_)
                                          : (VGT + ((size_t)(b*H_+h)*HD_)*S_);

    bf8_t qf[2];
    #pragma unroll
    for(int ks=0;ks<2;++ks) qf[ks] = *(const bf8_t*)(Qsrc + ks*32 + lg*8);

    float m_i[4]={-1e30f,-1e30f,-1e30f,-1e30f}, l_i[4]={0.f,0.f,0.f,0.f};
    f4_t acc_o[4];
    #pragma unroll
    for(int nf=0;nf<4;++nf) acc_o[nf]=(f4_t){0.f,0.f,0.f,0.f};

    const int njc = is_local ? 10 : 4;
    for(int jc=0;jc<njc;++jc){
        const int p0 = is_local ? ((jc==0) ? 0 : (s0-256+(jc-1)*64))
                                : (seg*256 + jc*64);
        if ((unsigned)p0 >= (unsigned)S_) continue;    // block-uniform skip
        {   // stage K + V tiles (64 rows x 128B each) via global_load_lds
            const int row0 = w*8 + (l>>3), chk = l&7;
            #pragma unroll
            for (int t = 0; t < 2; ++t) {
                int row = t*32 + row0;
                gld16(Ksrc + (size_t)(p0+row)*DM_ + ((chk ^ (row&7))<<3),
                      (char*)Kls + (t*32 + w*8)*128);
                gld16(Vsrc + (size_t)row*S_ + p0 + ((chk ^ (row&7))<<3),
                      (char*)Vls + (t*32 + w*8)*128);
            }
        }
        __syncthreads();                               // drain vmcnt(0)
        f4_t s4[4];
        #pragma unroll
        for(int cf=0;cf<4;++cf) s4[cf]=(f4_t){0.f,0.f,0.f,0.f};
        #pragma unroll
        for(int ks=0;ks<2;++ks)
            #pragma unroll
            for(int cf=0;cf<4;++cf){
                int r = cf*16+lc;
                bf8_t kf = *(const bf8_t*)((const char*)Kls + r*128 + (((ks*4+lg)^(r&7))<<4));
                s4[cf]=MFMA16(qf[ks],kf,s4[cf]);
            }
        if(is_local && jc>0){  // band mask: outside band -> -1e9; masked keys -> -10000
            #pragma unroll
            for(int cf=0;cf<4;++cf){
                int p = p0 + cf*16 + lc;
                float madd = (amask[b*S_+p]!=0) ? -10000.f : 0.f;
                #pragma unroll
                for(int i=0;i<4;++i){
                    int rel = p - (s0 + w*16 + lg*4 + i);
                    s4[cf][i] = (rel<-256 || rel>256) ? -1e9f : s4[cf][i]+madd;
                }
            }
        }
        float Pv[4][4];
        #pragma unroll
        for(int i=0;i<4;++i){
            float rm = fmaxf(fmaxf(s4[0][i],s4[1][i]),fmaxf(s4[2][i],s4[3][i]));
            rm = rmax16(rm);
            float mn = fmaxf(m_i[i], rm);
            float rs = 0.f;
            #pragma unroll
            for(int cf=0;cf<4;++cf){ float e=__expf(s4[cf][i]-mn); Pv[cf][i]=e; rs+=e; }
            rs = rsum16(rs);
            float f = __expf(m_i[i]-mn);
            l_i[i] = l_i[i]*f + rs;
            m_i[i] = mn;
            #pragma unroll
            for(int nf=0;nf<4;++nf) acc_o[nf][i]*=f;
        }
        #pragma unroll
        for(int cf=0;cf<4;++cf)
            #pragma unroll
            for(int i=0;i<4;++i){
                int qr = w*16+lg*4+i, p = cf*16+lc;
                Ps[qr*64 + ((((p>>3)^(qr&7))<<3) | (p&7))] = f2bf(Pv[cf][i]);
            }
        __syncthreads();                               // Ps visible
        #pragma unroll
        for(int ks=0;ks<2;++ks){
            int qr = w*16+lc;
            bf8_t pf = *(const bf8_t*)((const char*)Ps + qr*128 + (((ks*4+lg)^(qr&7))<<4));
            #pragma unroll
            for(int nf=0;nf<4;++nf){
                int dr = nf*16+lc;
                bf8_t vf = *(const bf8_t*)((const char*)Vls + dr*128 + (((ks*4+lg)^(dr&7))<<4));
                acc_o[nf] = MFMA16(pf, vf, acc_o[nf]);
            }
        }
        __syncthreads();                               // reads done before next stage
    }
    if (is_local) {
        #pragma unroll
        for(int i=0;i<4;++i){
            float inv = 1.f/l_i[i];
            float* orow = out + ((size_t)(b*S_ + s0 + w*16 + lg*4 + i))*DM_ + h*HD_;
            #pragma unroll
            for(int nf=0;nf<4;++nf) orow[nf*16+lc] = acc_o[nf][i]*inv;
        }
    } else {
        const int pid = (b*H_+h)*SEGN + seg;
        #pragma unroll
        for(int i=0;i<4;++i){
            int qrl = w*16 + lg*4 + i;
            #pragma unroll
            for(int nf=0;nf<4;++nf)
                part_o[(size_t)pid*4096 + qrl*64 + nf*16 + lc] = acc_o[nf][i];
            if(lc==0){
                part_m[pid*64+qrl] = m_i[i];
                part_l[pid*64+qrl] = l_i[i];
            }
        }
    }
}

__global__ __launch_bounds__(256) void global_combine(
    const float* __restrict__ part_m, const float* __restrict__ part_l,
    const float* __restrict__ part_o, float* __restrict__ out)
{
    const int bh = blockIdx.x;
    const int b = bh >> 3, h = bh & 7;
    const int tid = threadIdx.x;
    const int q = tid >> 2, d0 = (tid & 3) * 16;
    float mg = -1e30f;
    for (int s = 0; s < SEGN; ++s)
        mg = fmaxf(mg, part_m[(bh * SEGN + s) * 64 + q]);
    float lsum = 0.f, accv[16] = {};
    for (int s = 0; s < SEGN; ++s) {
        const int pid = bh * SEGN + s;
        float wgt = __expf(part_m[pid * 64 + q] - mg);
        lsum += wgt * part_l[pid * 64 + q];
        const float* op = part_o + (size_t)pid * 4096 + q * 64 + d0;
        #pragma unroll
        for (int t = 0; t < 4; ++t) {
            float tmp[4];
            *(float4*)tmp = *(const float4*)(op + t * 4);
            #pragma unroll
            for (int u = 0; u < 4; ++u) accv[t * 4 + u] += wgt * tmp[u];
        }
    }
    float inv = 1.f / lsum;
    float* orow = out + ((size_t)(b * S_ + q)) * DM_ + h * HD_ + d0;
    #pragma unroll
    for (int t = 0; t < 4; ++t) {
        float o[4];
        #pragma unroll
        for (int u = 0; u < 4; ++u) o[u] = accv[t * 4 + u] * inv;
        *(float4*)(orow + t * 4) = *(const float4*)o;
    }
}

extern "C" void kernel_launch(void* const* d_in, const int* in_sizes, int n_in,
                              void* d_out, int out_size, void* d_ws, size_t ws_size,
                              hipStream_t stream) {
    float* hidden = (float*)d_in[0];
    float* q  = (float*)d_in[1];
    float* k  = (float*)d_in[2];
    float* v  = (float*)d_in[3];
    const int* amask = (const int*)d_in[4];
    const float* Wq  = (const float*)d_in[5];  const float* bq  = (const float*)d_in[6];
    const float* Wk  = (const float*)d_in[7];  const float* bk  = (const float*)d_in[8];
    const float* Wv  = (const float*)d_in[9];  const float* bv  = (const float*)d_in[10];
    const float* Wqg = (const float*)d_in[11]; const float* bqg = (const float*)d_in[12];
    const float* Wkg = (const float*)d_in[13]; const float* bkg = (const float*)d_in[14];
    const float* Wvg = (const float*)d_in[15]; const float* bvg = (const float*)d_in[16];
    float* out = (float*)d_out;

    // ws layout (~54.5 MB peak):
    const size_t NE = (size_t)B_ * S_ * DM_;                  // 4194304
    unsigned short* Qbf  = (unsigned short*)d_ws;             // 8.4 MB
    unsigned short* Kbf  = Qbf  + NE;                         // 8.4 MB
    unsigned short* VT   = Kbf  + NE;                         // 8.4 MB
    unsigned short* KGbf = VT   + NE;                         // 8.4 MB
    unsigned short* VGT  = KGbf + NE;                         // 8.4 MB
    unsigned short* QGbf = VGT  + NE;                         // 128 KB
    unsigned* Wa = (unsigned*)(QGbf + (size_t)B_*G_*DM_);     // 6 MB
    unsigned* Wb = Wa + 6*262144;                             // 6 MB
    // Wa/Wb are dead after proj6 -> alias attention partials there:
    float* po = (float*)Wa;                                   // 4 MB
    float* pm = (float*)Wb;                                   // 64 KB
    float* pl = pm + B_*H_*SEGN*64;                           // 64 KB

    dim3 blk(256);
    // 1) in-place packed split of activations
    SplitArgs sa; sa.p[0]=hidden; sa.p[1]=q; sa.p[2]=k; sa.p[3]=v;
    hipLaunchKernelGGL(split_inplace, dim3(4*4096), blk, 0, stream, sa);
    // 2) weight expansion (q-scale folded into Wq/Wqg)
    WexpArgs we;
    we.src[0]=Wq; we.src[1]=Wk; we.src[2]=Wv; we.src[3]=Wkg; we.src[4]=Wvg; we.src[5]=Wqg;
    we.alpha[0]=0.125f; we.alpha[1]=1.f; we.alpha[2]=1.f;
    we.alpha[3]=1.f; we.alpha[4]=1.f; we.alpha[5]=0.125f;
    we.wa = Wa; we.wb = Wb;
    hipLaunchKernelGGL(wexpand, dim3(1536), blk, 0, stream, we);

    // 3) all six projections in one launch
    ProjBatch pp;
    pp.d[0] = { (const unsigned*)q,      Wa + 0*262144, Wb + 0*262144, bq,  Qbf,  nullptr, 0.125f, 1, 0, 64 };
    pp.d[1] = { (const unsigned*)k,      Wa + 1*262144, Wb + 1*262144, bk,  Kbf,  nullptr, 1.0f,   1, 0, 64 };
    pp.d[2] = { (const unsigned*)v,      Wa + 2*262144, Wb + 2*262144, bv,  nullptr, VT,   1.0f,   1, 1, 64 };
    pp.d[3] = { (const unsigned*)hidden, Wa + 3*262144, Wb + 3*262144, bkg, KGbf, nullptr, 1.0f,   0, 0, 64 };
    pp.d[4] = { (const unsigned*)hidden, Wa + 4*262144, Wb + 4*262144, bvg, nullptr, VGT,  1.0f,   0, 1, 64 };
    pp.d[5] = { (const unsigned*)hidden, Wa + 5*262144, Wb + 5*262144, bqg, QGbf, nullptr, 0.125f, 2, 0, 1  };
    hipLaunchKernelGGL(proj6, dim3(64,4,6), blk, 0, stream, pp);

    // 4) fused local + global attention
    hipLaunchKernelGGL(attn_fused, dim3(63+SEGN, H_, B_), blk, 0, stream,
                       Qbf, Kbf, VT, QGbf, KGbf, VGT, amask, out, pm, pl, po);

    // 5) combine global partials into rows 0..63
    hipLaunchKernelGGL(global_combine, dim3(B_ * H_), blk, 0, stream, pm, pl, po, out);
}

// Round 8
// 265.769 us; speedup vs baseline: 1.2814x; 1.1092x over previous
//
#include <hip/hip_runtime.h>
#include <cstdint>

#define S_   4096
#define B_   2
#define H_   8
#define HD_  64
#define DM_  512
#define G_   64
#define SEGN 16

typedef __attribute__((ext_vector_type(8))) short bf8_t;     // 8 bf16 (4 VGPR)
typedef __attribute__((ext_vector_type(4))) float f4_t;
typedef __attribute__((ext_vector_type(4))) unsigned u4_t;
#define MFMA16(A,Bv,C) __builtin_amdgcn_mfma_f32_16x16x32_bf16((A),(Bv),(C),0,0,0)

typedef const unsigned __attribute__((address_space(1)))* gp1_t;
typedef unsigned __attribute__((address_space(3)))* lp3_t;
static __device__ __forceinline__ void gld16(const void* g, void* l){
    __builtin_amdgcn_global_load_lds((gp1_t)g, (lp3_t)l, 16, 0, 0);
}

static __device__ __forceinline__ unsigned short f2bf(float x){   // RNE
    union { float f; unsigned u; } v; v.f = x;
    unsigned r = v.u + 0x7FFFu + ((v.u >> 16) & 1u);
    return (unsigned short)(r >> 16);
}
// packed trunc-split: low16 = bf16 hi-part, high16 = bf16 of residual
static __device__ __forceinline__ unsigned pksplit(float x){
    unsigned u = __float_as_uint(x);
    unsigned t = u & 0xFFFF0000u;
    float r = x - __uint_as_float(t);
    return (u >> 16) | (__float_as_uint(r) & 0xFFFF0000u);
}
static __device__ __forceinline__ float rmax16(float x){
    x=fmaxf(x,__shfl_xor(x,1)); x=fmaxf(x,__shfl_xor(x,2));
    x=fmaxf(x,__shfl_xor(x,4)); x=fmaxf(x,__shfl_xor(x,8)); return x;
}
static __device__ __forceinline__ float rsum16(float x){
    x+=__shfl_xor(x,1); x+=__shfl_xor(x,2); x+=__shfl_xor(x,4); x+=__shfl_xor(x,8); return x;
}

// perm 0: identity (B,S,D rows)  perm 1: (S,B,D)->(B,S,D)  perm 2: qg rows b*S+g
__device__ __forceinline__ int in_row_map(int m, int perm) {
    if (perm == 0) return m;
    if (perm == 1) { int b = m >> 12, s = m & 4095; return s * 2 + b; }
    { int b = m >> 6, g = m & 63; return b * S_ + g; }
}

// -------- in-place packed split of the 4 activation tensors (d_in restored every launch)
struct SplitArgs { float* p[4]; };
__global__ __launch_bounds__(256) void split_inplace(SplitArgs a){
    int t = blockIdx.x >> 12;                       // 4096 blocks per tensor
    int idx = (blockIdx.x & 4095) * 256 + threadIdx.x;
    float* p = a.p[t];
    float4 x = *(const float4*)(p + (size_t)idx * 4);
    unsigned o[4] = { pksplit(x.x), pksplit(x.y), pksplit(x.z), pksplit(x.w) };
    *(u4_t*)(p + (size_t)idx * 4) = *(const u4_t*)o;
}

// -------- weight expansion: W -> Wa=[w_hi,w_hi] u32 (A-split gives exact a.w_hi) ----
struct WexpArgs { const float* src[6]; float alpha[6]; unsigned* wa; };
__global__ __launch_bounds__(256) void wexpand(WexpArgs a){
    int g = blockIdx.x >> 8;                        // 256 blocks per tensor
    int idx = ((blockIdx.x & 255) * 256 + threadIdx.x) * 4;
    const float* s = a.src[g];
    float al = a.alpha[g];
    size_t base = (size_t)g * 262144 + idx;
    float4 x = *(const float4*)(s + idx);
    float xs[4] = { x.x*al, x.y*al, x.z*al, x.w*al };
    unsigned wa4[4];
    #pragma unroll
    for (int j = 0; j < 4; ++j) {
        unsigned u = __float_as_uint(xs[j]);
        wa4[j] = (u >> 16) | (u & 0xFFFF0000u);     // [w_hi, w_hi]
    }
    *(u4_t*)(a.wa + base) = *(const u4_t*)wa4;
}

// -------- projection GEMM: doubled-K bf16, A2=[a_hi,a_lo] x Wa=[w_hi,w_hi] ----------
// mode 0: out bf16 rows [m][512]     mode 1: out_t[b][h][d][S] bf16 (transposed)
struct ProjDesc {
    const unsigned* A2; const unsigned* Wa; const float* bias;
    unsigned short* out_r; unsigned short* out_t;
    float balpha; int perm; int mode; int mtiles;
};
struct ProjBatch { ProjDesc d[6]; };

__global__ __launch_bounds__(256) void proj6(ProjBatch pb){
    __shared__ unsigned Asl[128*32];   // [row][32 u32] = 128B rows, swizzled 16B chunks
    __shared__ unsigned Wasl[128*32];
    const ProjDesc d = pb.d[blockIdx.z];
    if ((int)blockIdx.x >= d.mtiles) return;
    const int tid = threadIdx.x;
    const int m0 = blockIdx.x*128, n0 = blockIdx.y*128;
    const int w = tid>>6, l = tid&63, wr = w>>1, wc = w&1, lg = l>>4, lc = l&15;
    const int grow = l>>3, gchk = l&7;              // 8 rows x 8 chunks per wave-issue

    f4_t acc[4][4];
    #pragma unroll
    for(int i=0;i<4;++i)
        #pragma unroll
        for(int j=0;j<4;++j) acc[i][j] = (f4_t){0.f,0.f,0.f,0.f};

    for (int k0 = 0; k0 < 16; ++k0) {
        __syncthreads();                             // prev step's LDS reads done
        #pragma unroll
        for (int t = 0; t < 4; ++t) {
            int row = t*32 + w*8 + grow;             // tile-local row 0..127
            int sw = (gchk ^ (row & 7)) << 2;        // pre-swizzled source chunk (u32)
            gld16(d.A2 + (size_t)in_row_map(m0+row, d.perm)*DM_ + k0*32 + sw,
                  (char*)Asl + (t*32 + w*8)*128);
            gld16(d.Wa + (size_t)(n0+row)*DM_ + k0*32 + sw,
                  (char*)Wasl + (t*32 + w*8)*128);
        }
        __syncthreads();                             // drains vmcnt(0)
        #pragma unroll
        for (int ks = 0; ks < 2; ++ks) {
            bf8_t af[4], wf[4];
            #pragma unroll
            for (int mf = 0; mf < 4; ++mf) {
                int r = wr*64 + mf*16 + lc;
                af[mf] = *(const bf8_t*)((const char*)Asl + r*128 + (((ks*4+lg) ^ (r&7))<<4));
            }
            #pragma unroll
            for (int nf = 0; nf < 4; ++nf) {
                int r = wc*64 + nf*16 + lc;
                wf[nf] = *(const bf8_t*)((const char*)Wasl + r*128 + (((ks*4+lg) ^ (r&7))<<4));
            }
            __builtin_amdgcn_s_setprio(1);
            #pragma unroll
            for (int nf = 0; nf < 4; ++nf)
                #pragma unroll
                for (int mf = 0; mf < 4; ++mf)
                    acc[mf][nf] = MFMA16(af[mf], wf[nf], acc[mf][nf]);
            __builtin_amdgcn_s_setprio(0);
        }
    }
    if (d.mode == 0) {
        #pragma unroll
        for(int nf=0;nf<4;++nf){
            int n = n0 + wc*64 + nf*16 + lc;
            float bv = d.bias[n] * d.balpha;
            #pragma unroll
            for(int mf=0;mf<4;++mf){
                int mb = m0 + wr*64 + mf*16 + lg*4;
                #pragma unroll
                for(int i=0;i<4;++i)
                    d.out_r[(size_t)(mb+i)*DM_ + n] = f2bf(acc[mf][nf][i] + bv);
            }
        }
    } else {
        #pragma unroll
        for(int nf=0;nf<4;++nf){
            int n = n0 + wc*64 + nf*16 + lc;
            int h = n>>6, dl = n&63;
            float bv = d.bias[n];
            #pragma unroll
            for(int mf=0;mf<4;++mf){
                int m = m0 + wr*64 + mf*16 + lg*4;
                int b = m>>12, s = m&4095;
                unsigned short q0=f2bf(acc[mf][nf][0]+bv), q1=f2bf(acc[mf][nf][1]+bv);
                unsigned short q2=f2bf(acc[mf][nf][2]+bv), q3=f2bf(acc[mf][nf][3]+bv);
                unsigned pkw[2] = { (unsigned)q0 | ((unsigned)q1<<16),
                                    (unsigned)q2 | ((unsigned)q3<<16) };
                *(uint2*)(d.out_t + ((size_t)((b*H_+h)*HD_ + dl))*S_ + s) = *(const uint2*)pkw;
            }
        }
    }
}

// ---------------- fused attention: x<63 -> local band tile; x>=63 -> global segment ----
__global__ __launch_bounds__(256) void attn_fused(
    const unsigned short* __restrict__ Qbf, const unsigned short* __restrict__ Kbf,
    const unsigned short* __restrict__ VT, const unsigned short* __restrict__ QGbf,
    const unsigned short* __restrict__ KGbf, const unsigned short* __restrict__ VGT,
    const int* __restrict__ amask, float* __restrict__ out,
    float* __restrict__ part_m, float* __restrict__ part_l, float* __restrict__ part_o)
{
    __shared__ unsigned short Kls[64*64];  // [p][64 bf16] 128B rows, swizzled chunks
    __shared__ unsigned short Vls[64*64];  // [d][64 bf16] 128B rows
    __shared__ unsigned short Ps[64*64];   // [q][64 bf16] 128B rows
    const int tid=threadIdx.x, b=blockIdx.z, h=blockIdx.y;
    const int w=tid>>6, l=tid&63, lg=l>>4, lc=l&15;
    const bool is_local = (int)blockIdx.x < 63;
    const int s0 = (blockIdx.x+1)*64;                  // local only
    const int seg = (int)blockIdx.x - 63;              // global only

    const unsigned short* Qsrc = is_local ? (Qbf + ((size_t)(b*S_ + s0 + w*16 + lc))*DM_ + h*HD_)
                                          : (QGbf + ((size_t)(b*G_ + w*16 + lc))*DM_ + h*HD_);
    const unsigned short* Ksrc = is_local ? (Kbf + (size_t)b*S_*DM_ + h*HD_)
                                          : (KGbf + (size_t)b*S_*DM_ + h*HD_);
    const unsigned short* Vsrc = is_local ? (VT + ((size_t)(b*H_+h)*HD_)*S_)
                                          : (VGT + ((size_t)(b*H_+h)*HD_)*S_);

    bf8_t qf[2];
    #pragma unroll
    for(int ks=0;ks<2;++ks) qf[ks] = *(const bf8_t*)(Qsrc + ks*32 + lg*8);

    float m_i[4]={-1e30f,-1e30f,-1e30f,-1e30f}, l_i[4]={0.f,0.f,0.f,0.f};
    f4_t acc_o[4];
    #pragma unroll
    for(int nf=0;nf<4;++nf) acc_o[nf]=(f4_t){0.f,0.f,0.f,0.f};

    const int njc = is_local ? 10 : 4;
    for(int jc=0;jc<njc;++jc){
        const int p0 = is_local ? ((jc==0) ? 0 : (s0-256+(jc-1)*64))
                                : (seg*256 + jc*64);
        if ((unsigned)p0 >= (unsigned)S_) continue;    // block-uniform skip
        {   // stage K + V tiles (64 rows x 128B each) via global_load_lds
            const int row0 = w*8 + (l>>3), chk = l&7;
            #pragma unroll
            for (int t = 0; t < 2; ++t) {
                int row = t*32 + row0;
                gld16(Ksrc + (size_t)(p0+row)*DM_ + ((chk ^ (row&7))<<3),
                      (char*)Kls + (t*32 + w*8)*128);
                gld16(Vsrc + (size_t)row*S_ + p0 + ((chk ^ (row&7))<<3),
                      (char*)Vls + (t*32 + w*8)*128);
            }
        }
        __syncthreads();                               // drain vmcnt(0)
        f4_t s4[4];
        #pragma unroll
        for(int cf=0;cf<4;++cf) s4[cf]=(f4_t){0.f,0.f,0.f,0.f};
        __builtin_amdgcn_s_setprio(1);
        #pragma unroll
        for(int ks=0;ks<2;++ks)
            #pragma unroll
            for(int cf=0;cf<4;++cf){
                int r = cf*16+lc;
                bf8_t kf = *(const bf8_t*)((const char*)Kls + r*128 + (((ks*4+lg)^(r&7))<<4));
                s4[cf]=MFMA16(qf[ks],kf,s4[cf]);
            }
        __builtin_amdgcn_s_setprio(0);
        if(is_local && jc>0){  // band mask: outside band -> -1e9; masked keys -> -10000
            #pragma unroll
            for(int cf=0;cf<4;++cf){
                int p = p0 + cf*16 + lc;
                float madd = (amask[b*S_+p]!=0) ? -10000.f : 0.f;
                #pragma unroll
                for(int i=0;i<4;++i){
                    int rel = p - (s0 + w*16 + lg*4 + i);
                    s4[cf][i] = (rel<-256 || rel>256) ? -1e9f : s4[cf][i]+madd;
                }
            }
        }
        float Pv[4][4];
        #pragma unroll
        for(int i=0;i<4;++i){
            float rm = fmaxf(fmaxf(s4[0][i],s4[1][i]),fmaxf(s4[2][i],s4[3][i]));
            rm = rmax16(rm);
            float mn = fmaxf(m_i[i], rm);
            float rs = 0.f;
            #pragma unroll
            for(int cf=0;cf<4;++cf){ float e=__expf(s4[cf][i]-mn); Pv[cf][i]=e; rs+=e; }
            rs = rsum16(rs);
            float f = __expf(m_i[i]-mn);
            l_i[i] = l_i[i]*f + rs;
            m_i[i] = mn;
            #pragma unroll
            for(int nf=0;nf<4;++nf) acc_o[nf][i]*=f;
        }
        #pragma unroll
        for(int cf=0;cf<4;++cf)
            #pragma unroll
            for(int i=0;i<4;++i){
                int qr = w*16+lg*4+i, p = cf*16+lc;
                Ps[qr*64 + ((((p>>3)^(qr&7))<<3) | (p&7))] = f2bf(Pv[cf][i]);
            }
        __syncthreads();                               // Ps visible
        __builtin_amdgcn_s_setprio(1);
        #pragma unroll
        for(int ks=0;ks<2;++ks){
            int qr = w*16+lc;
            bf8_t pf = *(const bf8_t*)((const char*)Ps + qr*128 + (((ks*4+lg)^(qr&7))<<4));
            #pragma unroll
            for(int nf=0;nf<4;++nf){
                int dr = nf*16+lc;
                bf8_t vf = *(const bf8_t*)((const char*)Vls + dr*128 + (((ks*4+lg)^(dr&7))<<4));
                acc_o[nf] = MFMA16(pf, vf, acc_o[nf]);
            }
        }
        __builtin_amdgcn_s_setprio(0);
        __syncthreads();                               // reads done before next stage
    }
    if (is_local) {
        #pragma unroll
        for(int i=0;i<4;++i){
            float inv = 1.f/l_i[i];
            float* orow = out + ((size_t)(b*S_ + s0 + w*16 + lg*4 + i))*DM_ + h*HD_;
            #pragma unroll
            for(int nf=0;nf<4;++nf) orow[nf*16+lc] = acc_o[nf][i]*inv;
        }
    } else {
        const int pid = (b*H_+h)*SEGN + seg;
        #pragma unroll
        for(int i=0;i<4;++i){
            int qrl = w*16 + lg*4 + i;
            #pragma unroll
            for(int nf=0;nf<4;++nf)
                part_o[(size_t)pid*4096 + qrl*64 + nf*16 + lc] = acc_o[nf][i];
            if(lc==0){
                part_m[pid*64+qrl] = m_i[i];
                part_l[pid*64+qrl] = l_i[i];
            }
        }
    }
}

__global__ __launch_bounds__(256) void global_combine(
    const float* __restrict__ part_m, const float* __restrict__ part_l,
    const float* __restrict__ part_o, float* __restrict__ out)
{
    const int bh = blockIdx.x >> 2, qq = blockIdx.x & 3;
    const int b = bh >> 3, h = bh & 7;
    const int tid = threadIdx.x;
    const int q = qq * 16 + (tid >> 4), d0 = (tid & 15) * 4;
    float mg = -1e30f;
    for (int s = 0; s < SEGN; ++s)
        mg = fmaxf(mg, part_m[(bh * SEGN + s) * 64 + q]);
    float lsum = 0.f, accv[4] = {};
    for (int s = 0; s < SEGN; ++s) {
        const int pid = bh * SEGN + s;
        float wgt = __expf(part_m[pid * 64 + q] - mg);
        lsum += wgt * part_l[pid * 64 + q];
        float tmp[4];
        *(float4*)tmp = *(const float4*)(part_o + (size_t)pid * 4096 + q * 64 + d0);
        #pragma unroll
        for (int u = 0; u < 4; ++u) accv[u] += wgt * tmp[u];
    }
    float inv = 1.f / lsum;
    float o[4];
    #pragma unroll
    for (int u = 0; u < 4; ++u) o[u] = accv[u] * inv;
    *(float4*)(out + ((size_t)(b * S_ + q)) * DM_ + h * HD_ + d0) = *(const float4*)o;
}

extern "C" void kernel_launch(void* const* d_in, const int* in_sizes, int n_in,
                              void* d_out, int out_size, void* d_ws, size_t ws_size,
                              hipStream_t stream) {
    float* hidden = (float*)d_in[0];
    float* q  = (float*)d_in[1];
    float* k  = (float*)d_in[2];
    float* v  = (float*)d_in[3];
    const int* amask = (const int*)d_in[4];
    const float* Wq  = (const float*)d_in[5];  const float* bq  = (const float*)d_in[6];
    const float* Wk  = (const float*)d_in[7];  const float* bk  = (const float*)d_in[8];
    const float* Wv  = (const float*)d_in[9];  const float* bv  = (const float*)d_in[10];
    const float* Wqg = (const float*)d_in[11]; const float* bqg = (const float*)d_in[12];
    const float* Wkg = (const float*)d_in[13]; const float* bkg = (const float*)d_in[14];
    const float* Wvg = (const float*)d_in[15]; const float* bvg = (const float*)d_in[16];
    float* out = (float*)d_out;

    // ws layout (~48 MB peak):
    const size_t NE = (size_t)B_ * S_ * DM_;                  // 4194304
    unsigned short* Qbf  = (unsigned short*)d_ws;             // 8.4 MB
    unsigned short* Kbf  = Qbf  + NE;                         // 8.4 MB
    unsigned short* VT   = Kbf  + NE;                         // 8.4 MB
    unsigned short* KGbf = VT   + NE;                         // 8.4 MB
    unsigned short* VGT  = KGbf + NE;                         // 8.4 MB
    unsigned short* QGbf = VGT  + NE;                         // 128 KB
    unsigned* Wa = (unsigned*)(QGbf + (size_t)B_*G_*DM_);     // 6 MB
    // Wa is dead after proj6 -> alias attention partials there:
    float* po = (float*)Wa;                                   // 4 MB
    float* pm = (float*)(Wa + 4*262144);                      // 64 KB
    float* pl = pm + B_*H_*SEGN*64;                           // 64 KB

    dim3 blk(256);
    // 1) in-place packed split of activations
    SplitArgs sa; sa.p[0]=hidden; sa.p[1]=q; sa.p[2]=k; sa.p[3]=v;
    hipLaunchKernelGGL(split_inplace, dim3(4*4096), blk, 0, stream, sa);
    // 2) weight expansion (q-scale folded into Wq/Wqg)
    WexpArgs we;
    we.src[0]=Wq; we.src[1]=Wk; we.src[2]=Wv; we.src[3]=Wkg; we.src[4]=Wvg; we.src[5]=Wqg;
    we.alpha[0]=0.125f; we.alpha[1]=1.f; we.alpha[2]=1.f;
    we.alpha[3]=1.f; we.alpha[4]=1.f; we.alpha[5]=0.125f;
    we.wa = Wa;
    hipLaunchKernelGGL(wexpand, dim3(1536), blk, 0, stream, we);

    // 3) all six projections in one launch
    ProjBatch pp;
    pp.d[0] = { (const unsigned*)q,      Wa + 0*262144, bq,  Qbf,  nullptr, 0.125f, 1, 0, 64 };
    pp.d[1] = { (const unsigned*)k,      Wa + 1*262144, bk,  Kbf,  nullptr, 1.0f,   1, 0, 64 };
    pp.d[2] = { (const unsigned*)v,      Wa + 2*262144, bv,  nullptr, VT,   1.0f,   1, 1, 64 };
    pp.d[3] = { (const unsigned*)hidden, Wa + 3*262144, bkg, KGbf, nullptr, 1.0f,   0, 0, 64 };
    pp.d[4] = { (const unsigned*)hidden, Wa + 4*262144, bvg, nullptr, VGT,  1.0f,   0, 1, 64 };
    pp.d[5] = { (const unsigned*)hidden, Wa + 5*262144, bqg, QGbf, nullptr, 0.125f, 2, 0, 1  };
    hipLaunchKernelGGL(proj6, dim3(64,4,6), blk, 0, stream, pp);

    // 4) fused local + global attention
    hipLaunchKernelGGL(attn_fused, dim3(63+SEGN, H_, B_), blk, 0, stream,
                       Qbf, Kbf, VT, QGbf, KGbf, VGT, amask, out, pm, pl, po);

    // 5) combine global partials into rows 0..63
    hipLaunchKernelGGL(global_combine, dim3(B_ * H_ * 4), blk, 0, stream, pm, pl, po, out);
}